// Round 12
// baseline (297.575 us; speedup 1.0000x reference)
//
#include <hip/hip_runtime.h>

// All tensors FLOAT32 (proven R5). GEMMs: bf16 MFMA (err 0.031 < 0.108 thr).
// 3-NN = lexicographic min-3 of (d2, idx) == lax.top_k stable tie-break;
// d2 exact rn form ((dx2+dy2)+dz2). Set semantics -> any enumeration order.
// Query: 8 lanes/target; ranges latched into SCALARS (no private arrays ->
// no scratch); ring stop via group-of-8 ballot (lane m2 >= group m2, so any
// lane passing the face-distance test implies the group passes -- conservative).

typedef __attribute__((ext_vector_type(8))) short bf16x8;
typedef __attribute__((ext_vector_type(4))) float f32x4;

__device__ __forceinline__ unsigned short f2bf(float f) {
    union { float f; unsigned u; } v; v.f = f;
    return (unsigned short)((v.u + 0x7fffu + ((v.u >> 16) & 1u)) >> 16); // RNE
}
__device__ __forceinline__ unsigned pack2(float a, float b) {
    return (unsigned)f2bf(a) | ((unsigned)f2bf(b) << 16);
}

// ---------- fused grid build (R11-proven): 4 blocks = 2 grids x 2 batches ----------
__global__ __launch_bounds__(1024)
void build_grid_kernel(const float* __restrict__ p4, const float* __restrict__ p2,
                       float4* __restrict__ sorted4, int* __restrict__ start4,
                       float4* __restrict__ sorted2, int* __restrict__ start2,
                       float* __restrict__ st1, float* __restrict__ st2) {
    __shared__ int A[1024], B[1024];
    int bx = blockIdx.x, t = threadIdx.x;
    int isG2 = bx >> 1, b = bx & 1;
    const float* pts = (isG2 ? p2 : p4);
    int Ns = isG2 ? 4096 : 2048;
    int G  = isG2 ? 10 : 8;
    int nc = G * G * G;
    float invh = (float)G / 70.0f;
    float4* sorted = (isG2 ? sorted2 : sorted4) + b * Ns;
    int* start = (isG2 ? start2 : start4) + b * (nc + 1);
    const float* pb = pts + b * Ns * 3;

    if (bx == 0 && t < 256) st1[t] = 0.f;
    if (bx == 1 && t < 256) st2[t] = 0.f;

    A[t] = 0;
    __syncthreads();
    for (int i = t; i < Ns; i += 1024) {
        float x = pb[i*3], y = pb[i*3+1], z = pb[i*3+2];
        int cx = min(G-1, max(0, (int)(x*invh)));
        int cy = min(G-1, max(0, (int)(y*invh)));
        int cz = min(G-1, max(0, (int)(z*invh)));
        atomicAdd(&A[(cz*G + cy)*G + cx], 1);
    }
    __syncthreads();
    int* src = A; int* dst = B;
    for (int off = 1; off < 1024; off <<= 1) {
        dst[t] = src[t] + ((t >= off) ? src[t - off] : 0);
        __syncthreads();
        int* tmp = src; src = dst; dst = tmp;
    }
    int ex = (t == 0) ? 0 : src[t - 1];
    if (t < nc) { start[t] = ex; dst[t] = ex; }
    if (t == 0) start[nc] = src[nc - 1];
    __syncthreads();
    for (int i = t; i < Ns; i += 1024) {
        float x = pb[i*3], y = pb[i*3+1], z = pb[i*3+2];
        int cx = min(G-1, max(0, (int)(x*invh)));
        int cy = min(G-1, max(0, (int)(y*invh)));
        int cz = min(G-1, max(0, (int)(z*invh)));
        int pos = atomicAdd(&dst[(cz*G + cy)*G + cx], 1);
        sorted[pos] = make_float4(x, y, z, __int_as_float(i));
    }
}

// ---------- fused 3-NN query+gather v2: 8 lanes/target, scalar latches ----------
template<int G>
__global__ __launch_bounds__(256)
void nn_query_gather_kernel(const float* __restrict__ tp, int Nt,
                            const float4* __restrict__ sorted,
                            const int* __restrict__ start, int Ns,
                            const float* __restrict__ feats, float* __restrict__ out) {
    const float h = 70.0f / G, invh = (float)G / 70.0f;
    int tid = threadIdx.x;
    int l = tid & 7, g = tid >> 3;
    int b = blockIdx.y;
    int t = blockIdx.x * 32 + g;
    int tg = b * Nt + t;
    int grpShift = (tid & 63) & ~7;   // wave-lane base of this 8-lane group
    float tx = tp[tg*3], ty = tp[tg*3+1], tz = tp[tg*3+2];
    int cx = min(G-1, max(0, (int)(tx*invh)));
    int cy = min(G-1, max(0, (int)(ty*invh)));
    int cz = min(G-1, max(0, (int)(tz*invh)));
    const float4* sb = sorted + b * Ns;
    const int* stb = start + b * (G*G*G + 1);

    float m0 = 3.4e38f, m1 = 3.4e38f, m2 = 3.4e38f;
    int j0 = 0x7fffffff, j1 = 0x7fffffff, j2 = 0x7fffffff;

    auto lexins = [&](float d, int ix) {
        bool lt0 = (d < m0) || (d == m0 && ix < j0);
        bool lt1 = (d < m1) || (d == m1 && ix < j1);
        bool lt2 = (d < m2) || (d == m2 && ix < j2);
        m2 = lt1 ? m1 : (lt2 ? d : m2);  j2 = lt1 ? j1 : (lt2 ? ix : j2);
        m1 = lt0 ? m0 : (lt1 ? d : m1);  j1 = lt0 ? j0 : (lt1 ? ix : j1);
        m0 = lt0 ? d : m0;               j0 = lt0 ? ix : j0;
    };
    auto scanRange = [&](int p0, int p1) {
        for (int p = p0; p < p1; ++p) {
            float4 s = sb[p];
            float ddx = tx - s.x, ddy = ty - s.y, ddz = tz - s.z;
            float d2 = __fadd_rn(__fadd_rn(__fmul_rn(ddx,ddx), __fmul_rn(ddy,ddy)),
                                 __fmul_rn(ddz,ddz));
            lexins(d2, __float_as_int(s.w));
        }
    };

    for (int R = 0; R < G; ++R) {
        int p0a = 0, p1a = 0, p0b = 0, p1b = 0;
        int nm = 0, k = 0;
        int zlo = max(cz - R, 0), zhi = min(cz + R, G - 1);
        int ylo = max(cy - R, 0), yhi = min(cy + R, G - 1);
        for (int z = zlo; z <= zhi; ++z) {
            bool zedge = (z == cz - R) || (z == cz + R);
            for (int y = ylo; y <= yhi; ++y) {
                bool edge = zedge || (y == cy - R) || (y == cy + R);
                int rowb = (z*G + y)*G;
                if (edge) {
                    int x0 = max(cx - R, 0), x1 = min(cx + R, G - 1);
                    if ((k & 7) == l) {
                        int p0 = stb[rowb + x0], p1 = stb[rowb + x1 + 1];
                        if (nm == 0)      { p0a = p0; p1a = p1; }
                        else if (nm == 1) { p0b = p0; p1b = p1; }
                        else scanRange(p0, p1);   // only possible for R>=2 (rare)
                        ++nm;
                    }
                    ++k;
                } else {
                    int xm = cx - R, xp = cx + R;
                    if (xm >= 0) {
                        if ((k & 7) == l) {
                            int p0 = stb[rowb + xm], p1 = stb[rowb + xm + 1];
                            if (nm == 0)      { p0a = p0; p1a = p1; }
                            else if (nm == 1) { p0b = p0; p1b = p1; }
                            else scanRange(p0, p1);
                            ++nm;
                        }
                        ++k;
                    }
                    if (xp <= G - 1) {
                        if ((k & 7) == l) {
                            int p0 = stb[rowb + xp], p1 = stb[rowb + xp + 1];
                            if (nm == 0)      { p0a = p0; p1a = p1; }
                            else if (nm == 1) { p0b = p0; p1b = p1; }
                            else scanRange(p0, p1);
                            ++nm;
                        }
                        ++k;
                    }
                }
            }
        }
        // all 8 lanes stream their latched ranges concurrently
        if (nm > 0) scanRange(p0a, p1a);
        if (nm > 1) scanRange(p0b, p1b);

        // group stop via ballot: lane m2 >= group m2, so any lane passing => stop
        float fx0 = (cx - R <= 0)     ? 3.4e38f : tx - (float)(cx - R) * h;
        float fx1 = (cx + R >= G - 1) ? 3.4e38f : (float)(cx + R + 1) * h - tx;
        float fy0 = (cy - R <= 0)     ? 3.4e38f : ty - (float)(cy - R) * h;
        float fy1 = (cy + R >= G - 1) ? 3.4e38f : (float)(cy + R + 1) * h - ty;
        float fz0 = (cz - R <= 0)     ? 3.4e38f : tz - (float)(cz - R) * h;
        float fz1 = (cz + R >= G - 1) ? 3.4e38f : (float)(cz + R + 1) * h - tz;
        float dl = fminf(fminf(fminf(fx0, fx1), fminf(fy0, fy1)), fminf(fz0, fz1));
        bool cond = (m2 < 3.3e38f) && (dl > 1.0e19f || m2 <= dl * dl * 0.9999f);
        unsigned long long bal = __ballot(cond);
        if ((bal >> grpShift) & 0xFFull) break;
    }

    // final exact lex merge across the 8 lanes (disjoint multisets)
    #pragma unroll
    for (int mask = 1; mask <= 4; mask <<= 1) {
        float o0 = __shfl_xor(m0, mask), o1 = __shfl_xor(m1, mask), o2 = __shfl_xor(m2, mask);
        int   q0 = __shfl_xor(j0, mask), q1 = __shfl_xor(j1, mask), q2 = __shfl_xor(j2, mask);
        lexins(o0, q0); lexins(o1, q1); lexins(o2, q2);
    }

    float d0 = sqrtf(fmaxf(m0, 0.f));
    float d1 = sqrtf(fmaxf(m1, 0.f));
    float d2s = sqrtf(fmaxf(m2, 0.f));
    float w0 = 1.f / (d0 + 1e-8f);
    float w1 = 1.f / (d1 + 1e-8f);
    float w2 = 1.f / (d2s + 1e-8f);
    float wsum = w0 + w1 + w2;
    w0 /= wsum; w1 /= wsum; w2 /= wsum;

    // fused gather: lane l covers channels [l*16, l*16+16)
    int base = b * Ns * 128;
    const float4* F0 = (const float4*)&feats[base + j0 * 128];
    const float4* F1 = (const float4*)&feats[base + j1 * 128];
    const float4* F2 = (const float4*)&feats[base + j2 * 128];
    float4* O = (float4*)&out[tg * 128];
    #pragma unroll
    for (int q = 0; q < 4; ++q) {
        int ci = l * 4 + q;
        float4 a = F0[ci], bb = F1[ci], cc = F2[ci];
        float4 o;
        o.x = w0*a.x + w1*bb.x + w2*cc.x;
        o.y = w0*a.y + w1*bb.y + w2*cc.y;
        o.z = w0*a.z + w1*bb.z + w2*cc.z;
        o.w = w0*a.w + w1*bb.w + w2*cc.w;
        O[ci] = o;
    }
}

// ---------- GEMM A (MFMA bf16, +fused BN stats): H = [L|R] @ W^T ---------- (R9-proven)
__global__ __launch_bounds__(256)
void gemm_a_kernel(const float* __restrict__ L, const float* __restrict__ R,
                   const float* __restrict__ W, float* __restrict__ H,
                   float* __restrict__ st) {
    __shared__ short Asm[4096];
    __shared__ short Bsm[2048];
    int tid = threadIdx.x;
    int lane = tid & 63, w = tid >> 6;
    int m16 = lane & 15, quad = lane >> 4;
    int rowBase = blockIdx.y * 128;
    int colBase = blockIdx.x * 64;
    f32x4 acc[2][4] = {};
    for (int k0 = 0; k0 < 256; k0 += 32) {
        #pragma unroll
        for (int i = 0; i < 2; ++i) {
            int u = tid + i * 256;
            int r = u >> 2, g = u & 3;
            const float* p = (k0 < 128) ? &L[(rowBase + r) * 128 + k0 + g * 8]
                                        : &R[(rowBase + r) * 128 + (k0 - 128) + g * 8];
            float4 x = *(const float4*)p, y = *(const float4*)(p + 4);
            uint4 pk = make_uint4(pack2(x.x, x.y), pack2(x.z, x.w),
                                  pack2(y.x, y.y), pack2(y.z, y.w));
            int blk = (r >> 4) * 64 + (r & 15) * 4 + g;
            *(uint4*)&Asm[blk * 8] = pk;
        }
        {
            int n = tid >> 2, g = tid & 3;
            const float* p = &W[(colBase + n) * 256 + k0 + g * 8];
            float4 x = *(const float4*)p, y = *(const float4*)(p + 4);
            uint4 pk = make_uint4(pack2(x.x, x.y), pack2(x.z, x.w),
                                  pack2(y.x, y.y), pack2(y.z, y.w));
            int blk = (n >> 4) * 64 + (n & 15) * 4 + g;
            *(uint4*)&Bsm[blk * 8] = pk;
        }
        __syncthreads();
        bf16x8 a0 = *(const bf16x8*)&Asm[((2 * w + 0) * 64 + m16 * 4 + quad) * 8];
        bf16x8 a1 = *(const bf16x8*)&Asm[((2 * w + 1) * 64 + m16 * 4 + quad) * 8];
        #pragma unroll
        for (int ct = 0; ct < 4; ++ct) {
            bf16x8 bf = *(const bf16x8*)&Bsm[(ct * 64 + m16 * 4 + quad) * 8];
            acc[0][ct] = __builtin_amdgcn_mfma_f32_16x16x32_bf16(a0, bf, acc[0][ct], 0, 0, 0);
            acc[1][ct] = __builtin_amdgcn_mfma_f32_16x16x32_bf16(a1, bf, acc[1][ct], 0, 0, 0);
        }
        __syncthreads();
    }
    #pragma unroll
    for (int rt = 0; rt < 2; ++rt)
        #pragma unroll
        for (int r = 0; r < 4; ++r) {
            int row = rowBase + (2 * w + rt) * 16 + quad * 4 + r;
            #pragma unroll
            for (int ct = 0; ct < 4; ++ct)
                H[row * 128 + colBase + ct * 16 + m16] = acc[rt][ct][r];
        }
    float* ssum = (float*)Asm;
    float* ssq  = (float*)Asm + 1024;
    #pragma unroll
    for (int ct = 0; ct < 4; ++ct) {
        float s = 0.f, q = 0.f;
        #pragma unroll
        for (int rt = 0; rt < 2; ++rt)
            #pragma unroll
            for (int r = 0; r < 4; ++r) {
                float v = acc[rt][ct][r];
                s += v; q += v * v;
            }
        ssum[(w * 4 + quad) * 64 + ct * 16 + m16] = s;
        ssq [(w * 4 + quad) * 64 + ct * 16 + m16] = q;
    }
    __syncthreads();
    if (tid < 64) {
        float s = 0.f, q = 0.f;
        #pragma unroll
        for (int i = 0; i < 16; ++i) { s += ssum[i * 64 + tid]; q += ssq[i * 64 + tid]; }
        atomicAdd(&st[colBase + tid], s);
        atomicAdd(&st[128 + colBase + tid], q);
    }
}

// ---------- GEMM B (MFMA bf16, finalize fused): out = relu(BN(H)) @ W^T + bias ----------
__global__ __launch_bounds__(256)
void gemm_b_kernel(const float* __restrict__ Hin, const float* __restrict__ st,
                   const float* __restrict__ gam, const float* __restrict__ bet,
                   float invN, const float* __restrict__ W,
                   const float* __restrict__ bias, float* __restrict__ out) {
    __shared__ short Asm[4096];
    __shared__ short Bsm[2048];
    __shared__ float ssc[128], ssf[128];
    int tid = threadIdx.x;
    if (tid < 128) {   // finalize (identical arithmetic to the old kernel)
        float mu = st[tid] * invN;
        float var = st[128 + tid] * invN - mu * mu;
        float rstd = rsqrtf(fmaxf(var, 0.f) + 1e-5f);
        float sc = rstd * gam[tid];
        ssc[tid] = sc;
        ssf[tid] = bet[tid] - mu * sc;
    }
    __syncthreads();
    int lane = tid & 63, w = tid >> 6;
    int m16 = lane & 15, quad = lane >> 4;
    int rowBase = blockIdx.y * 128;
    int colBase = blockIdx.x * 64;
    f32x4 acc[2][4] = {};
    for (int k0 = 0; k0 < 128; k0 += 32) {
        #pragma unroll
        for (int i = 0; i < 2; ++i) {
            int u = tid + i * 256;
            int r = u >> 2, g = u & 3;
            int c = k0 + g * 8;
            const float* p = &Hin[(rowBase + r) * 128 + c];
            float4 x = *(const float4*)p, y = *(const float4*)(p + 4);
            float h0 = fmaxf(x.x * ssc[c+0] + ssf[c+0], 0.f);
            float h1 = fmaxf(x.y * ssc[c+1] + ssf[c+1], 0.f);
            float h2 = fmaxf(x.z * ssc[c+2] + ssf[c+2], 0.f);
            float h3 = fmaxf(x.w * ssc[c+3] + ssf[c+3], 0.f);
            float h4 = fmaxf(y.x * ssc[c+4] + ssf[c+4], 0.f);
            float h5 = fmaxf(y.y * ssc[c+5] + ssf[c+5], 0.f);
            float h6 = fmaxf(y.z * ssc[c+6] + ssf[c+6], 0.f);
            float h7 = fmaxf(y.w * ssc[c+7] + ssf[c+7], 0.f);
            uint4 pk = make_uint4(pack2(h0, h1), pack2(h2, h3),
                                  pack2(h4, h5), pack2(h6, h7));
            int blk = (r >> 4) * 64 + (r & 15) * 4 + g;
            *(uint4*)&Asm[blk * 8] = pk;
        }
        {
            int n = tid >> 2, g = tid & 3;
            const float* p = &W[(colBase + n) * 128 + k0 + g * 8];
            float4 x = *(const float4*)p, y = *(const float4*)(p + 4);
            uint4 pk = make_uint4(pack2(x.x, x.y), pack2(x.z, x.w),
                                  pack2(y.x, y.y), pack2(y.z, y.w));
            int blk = (n >> 4) * 64 + (n & 15) * 4 + g;
            *(uint4*)&Bsm[blk * 8] = pk;
        }
        __syncthreads();
        bf16x8 a0 = *(const bf16x8*)&Asm[((2 * w + 0) * 64 + m16 * 4 + quad) * 8];
        bf16x8 a1 = *(const bf16x8*)&Asm[((2 * w + 1) * 64 + m16 * 4 + quad) * 8];
        #pragma unroll
        for (int ct = 0; ct < 4; ++ct) {
            bf16x8 bf = *(const bf16x8*)&Bsm[(ct * 64 + m16 * 4 + quad) * 8];
            acc[0][ct] = __builtin_amdgcn_mfma_f32_16x16x32_bf16(a0, bf, acc[0][ct], 0, 0, 0);
            acc[1][ct] = __builtin_amdgcn_mfma_f32_16x16x32_bf16(a1, bf, acc[1][ct], 0, 0, 0);
        }
        __syncthreads();
    }
    #pragma unroll
    for (int ct = 0; ct < 4; ++ct) {
        float bv = bias[colBase + ct * 16 + m16];
        #pragma unroll
        for (int rt = 0; rt < 2; ++rt)
            #pragma unroll
            for (int r = 0; r < 4; ++r) {
                int row = rowBase + (2 * w + rt) * 16 + quad * 4 + r;
                out[row * 128 + colBase + ct * 16 + m16] = acc[rt][ct][r] + bv;
            }
    }
}

extern "C" void kernel_launch(void* const* d_in, const int* in_sizes, int n_in,
                              void* d_out, int out_size, void* d_ws, size_t ws_size,
                              hipStream_t stream) {
    const float* pts_r1 = (const float*)d_in[0];   // (2,8192,3)
    const float* pts_r2 = (const float*)d_in[1];   // (2,4096,3)
    const float* pts_r4 = (const float*)d_in[2];   // (2,2048,3)
    const float* feat0  = (const float*)d_in[3];   // (16384,128)
    const float* feat1  = (const float*)d_in[4];   // (8192,128)
    const float* feat2  = (const float*)d_in[5];   // (4096,128)
    const float* w3a = (const float*)d_in[6];      // (128,256)
    const float* g3  = (const float*)d_in[7];
    const float* b3  = (const float*)d_in[8];
    const float* w3b = (const float*)d_in[9];      // (128,128)
    const float* bb3 = (const float*)d_in[10];
    const float* w4a = (const float*)d_in[11];     // (128,256)
    const float* g4  = (const float*)d_in[12];
    const float* b4  = (const float*)d_in[13];
    const float* w4b = (const float*)d_in[14];     // (128,128)
    const float* bb4 = (const float*)d_in[15];

    float* wsf = (float*)d_ws;
    float4* sorted4 = (float4*)(wsf + 0);        // 2*2048 float4
    float4* sorted2 = (float4*)(wsf + 16384);    // 2*4096 float4
    int*   start4   = (int*)(wsf + 49152);       // 2*513 -> pad 1152
    int*   start2   = (int*)(wsf + 50304);       // 2*1001 -> pad 2048
    float* st1 = wsf + 52352;                    // 256 (sum | sumsq)
    float* st2 = wsf + 52864;                    // 256
    float* f2i = wsf + 53376;                    // 8192*128
    float* H1  = wsf + 1101952;                  // 8192*128
    float* n3  = wsf + 2150528;                  // 8192*128
    float* n3i = wsf + 53376;                    // 16384*128 (over f2i+H1, both dead)
    float* H2  = wsf + 2150528;                  // 16384*128 (over n3, dead by then)

    // 1. build both grids (+zero stats)
    build_grid_kernel<<<4, 1024, 0, stream>>>(pts_r4, pts_r2, sorted4, start4,
                                              sorted2, start2, st1, st2);
    // 2. interp #1: feat2 (pts_r4 grid, G=8) -> pts_r2 targets
    nn_query_gather_kernel<8><<<dim3(128, 2), 256, 0, stream>>>(pts_r2, 4096, sorted4,
                                                                start4, 2048, feat2, f2i);
    // 3. fnode 3
    gemm_a_kernel<<<dim3(2, 64), 256, 0, stream>>>(feat1, f2i, w3a, H1, st1);
    gemm_b_kernel<<<dim3(2, 64), 256, 0, stream>>>(H1, st1, g3, b3, 1.f / 8192.f,
                                                   w3b, bb3, n3);
    // 4. interp #2: n3 (pts_r2 grid, G=10) -> pts_r1 targets
    nn_query_gather_kernel<10><<<dim3(256, 2), 256, 0, stream>>>(pts_r1, 8192, sorted2,
                                                                 start2, 4096, n3, n3i);
    // 5. fnode 4
    gemm_a_kernel<<<dim3(2, 128), 256, 0, stream>>>(feat0, n3i, w4a, H2, st2);
    gemm_b_kernel<<<dim3(2, 128), 256, 0, stream>>>(H2, st2, g4, b4, 1.f / 16384.f,
                                                    w4b, bb4, (float*)d_out);
}

// Round 13
// 216.983 us; speedup vs baseline: 1.3714x; 1.3714x over previous
//
#include <hip/hip_runtime.h>

// All tensors FLOAT32 (proven R5). GEMMs: bf16 MFMA (err 0.031 < 0.108 thr).
// 3-NN = lexicographic min-3 of (d2, idx) == lax.top_k stable tie-break;
// d2 exact rn form ((dx2+dy2)+dz2). Set semantics -> any enumeration order.
// Query v3: unconditional 3x3x3 box scan (9 row-merged ranges over 8 lanes),
// ONE exact butterfly merge, ONE stop test on the exact group 3rd-min
// (R12 bug: lane-local m2 was too loose -> ring-2 explosion). Rare fallback
// rings use fresh per-ring locals (disjoint -> no duplicate insertion).

typedef __attribute__((ext_vector_type(8))) short bf16x8;
typedef __attribute__((ext_vector_type(4))) float f32x4;

__device__ __forceinline__ unsigned short f2bf(float f) {
    union { float f; unsigned u; } v; v.f = f;
    return (unsigned short)((v.u + 0x7fffu + ((v.u >> 16) & 1u)) >> 16); // RNE
}
__device__ __forceinline__ unsigned pack2(float a, float b) {
    return (unsigned)f2bf(a) | ((unsigned)f2bf(b) << 16);
}

// ---------- fused grid build (R11-proven): 4 blocks = 2 grids x 2 batches ----------
__global__ __launch_bounds__(1024)
void build_grid_kernel(const float* __restrict__ p4, const float* __restrict__ p2,
                       float4* __restrict__ sorted4, int* __restrict__ start4,
                       float4* __restrict__ sorted2, int* __restrict__ start2,
                       float* __restrict__ st1, float* __restrict__ st2) {
    __shared__ int A[1024], B[1024];
    int bx = blockIdx.x, t = threadIdx.x;
    int isG2 = bx >> 1, b = bx & 1;
    const float* pts = (isG2 ? p2 : p4);
    int Ns = isG2 ? 4096 : 2048;
    int G  = isG2 ? 10 : 8;
    int nc = G * G * G;
    float invh = (float)G / 70.0f;
    float4* sorted = (isG2 ? sorted2 : sorted4) + b * Ns;
    int* start = (isG2 ? start2 : start4) + b * (nc + 1);
    const float* pb = pts + b * Ns * 3;

    if (bx == 0 && t < 256) st1[t] = 0.f;
    if (bx == 1 && t < 256) st2[t] = 0.f;

    A[t] = 0;
    __syncthreads();
    for (int i = t; i < Ns; i += 1024) {
        float x = pb[i*3], y = pb[i*3+1], z = pb[i*3+2];
        int cx = min(G-1, max(0, (int)(x*invh)));
        int cy = min(G-1, max(0, (int)(y*invh)));
        int cz = min(G-1, max(0, (int)(z*invh)));
        atomicAdd(&A[(cz*G + cy)*G + cx], 1);
    }
    __syncthreads();
    int* src = A; int* dst = B;
    for (int off = 1; off < 1024; off <<= 1) {
        dst[t] = src[t] + ((t >= off) ? src[t - off] : 0);
        __syncthreads();
        int* tmp = src; src = dst; dst = tmp;
    }
    int ex = (t == 0) ? 0 : src[t - 1];
    if (t < nc) { start[t] = ex; dst[t] = ex; }
    if (t == 0) start[nc] = src[nc - 1];
    __syncthreads();
    for (int i = t; i < Ns; i += 1024) {
        float x = pb[i*3], y = pb[i*3+1], z = pb[i*3+2];
        int cx = min(G-1, max(0, (int)(x*invh)));
        int cy = min(G-1, max(0, (int)(y*invh)));
        int cz = min(G-1, max(0, (int)(z*invh)));
        int pos = atomicAdd(&dst[(cz*G + cy)*G + cx], 1);
        sorted[pos] = make_float4(x, y, z, __int_as_float(i));
    }
}

// ---------- fused 3-NN query+gather v3 ----------
template<int G>
__global__ __launch_bounds__(256)
void nn_query_gather_kernel(const float* __restrict__ tp, int Nt,
                            const float4* __restrict__ sorted,
                            const int* __restrict__ start, int Ns,
                            const float* __restrict__ feats, float* __restrict__ out) {
    const float h = 70.0f / G, invh = (float)G / 70.0f;
    int tid = threadIdx.x;
    int l = tid & 7, g = tid >> 3;
    int b = blockIdx.y;
    int t = blockIdx.x * 32 + g;
    int tg = b * Nt + t;
    float tx = tp[tg*3], ty = tp[tg*3+1], tz = tp[tg*3+2];
    int cx = min(G-1, max(0, (int)(tx*invh)));
    int cy = min(G-1, max(0, (int)(ty*invh)));
    int cz = min(G-1, max(0, (int)(tz*invh)));
    const float4* sb = sorted + b * Ns;
    const int* stb = start + b * (G*G*G + 1);

    float m0 = 3.4e38f, m1 = 3.4e38f, m2 = 3.4e38f;
    int j0 = 0x7fffffff, j1 = 0x7fffffff, j2 = 0x7fffffff;

    auto lexM = [&](float d, int ix) {
        bool lt0 = (d < m0) || (d == m0 && ix < j0);
        bool lt1 = (d < m1) || (d == m1 && ix < j1);
        bool lt2 = (d < m2) || (d == m2 && ix < j2);
        m2 = lt1 ? m1 : (lt2 ? d : m2);  j2 = lt1 ? j1 : (lt2 ? ix : j2);
        m1 = lt0 ? m0 : (lt1 ? d : m1);  j1 = lt0 ? j0 : (lt1 ? ix : j1);
        m0 = lt0 ? d : m0;               j0 = lt0 ? ix : j0;
    };
    auto scanM = [&](int p0, int p1) {
        for (int p = p0; p < p1; ++p) {
            float4 s = sb[p];
            float ddx = tx - s.x, ddy = ty - s.y, ddz = tz - s.z;
            float d2 = __fadd_rn(__fadd_rn(__fmul_rn(ddx,ddx), __fmul_rn(ddy,ddy)),
                                 __fmul_rn(ddz,ddz));
            lexM(d2, __float_as_int(s.w));
        }
    };
    auto mergeM = [&]() {
        #pragma unroll
        for (int mask = 1; mask <= 4; mask <<= 1) {
            float o0 = __shfl_xor(m0, mask), o1 = __shfl_xor(m1, mask), o2 = __shfl_xor(m2, mask);
            int   q0 = __shfl_xor(j0, mask), q1 = __shfl_xor(j1, mask), q2 = __shfl_xor(j2, mask);
            lexM(o0, q0); lexM(o1, q1); lexM(o2, q2);
        }
    };
    auto faceD = [&](int R) -> float {
        float fx0 = (cx - R <= 0)     ? 3.4e38f : tx - (float)(cx - R) * h;
        float fx1 = (cx + R >= G - 1) ? 3.4e38f : (float)(cx + R + 1) * h - tx;
        float fy0 = (cy - R <= 0)     ? 3.4e38f : ty - (float)(cy - R) * h;
        float fy1 = (cy + R >= G - 1) ? 3.4e38f : (float)(cy + R + 1) * h - ty;
        float fz0 = (cz - R <= 0)     ? 3.4e38f : tz - (float)(cz - R) * h;
        float fz1 = (cz + R >= G - 1) ? 3.4e38f : (float)(cz + R + 1) * h - tz;
        return fminf(fminf(fminf(fx0, fx1), fminf(fy0, fy1)), fminf(fz0, fz1));
    };

    // --- unconditional 3x3x3 box scan: 9 row-merged ranges over 8 lanes ---
    {
        int x0 = max(cx - 1, 0), x1 = min(cx + 1, G - 1);
        int zlo = max(cz - 1, 0), zhi = min(cz + 1, G - 1);
        int ylo = max(cy - 1, 0), yhi = min(cy + 1, G - 1);
        int p0a = 0, p1a = 0, p0b = 0, p1b = 0;
        int nm = 0, k = 0;
        for (int z = zlo; z <= zhi; ++z)
            for (int y = ylo; y <= yhi; ++y) {
                if ((k & 7) == l) {
                    int rowb = (z*G + y)*G;
                    int p0 = stb[rowb + x0], p1 = stb[rowb + x1 + 1];
                    if (nm == 0) { p0a = p0; p1a = p1; }
                    else         { p0b = p0; p1b = p1; }   // <=9 rows -> nm<=2
                    ++nm;
                }
                ++k;
            }
        if (nm > 0) scanM(p0a, p1a);
        if (nm > 1) scanM(p0b, p1b);
    }
    mergeM();   // all 8 lanes now hold the exact union top-3
    float dl = faceD(1);
    bool done = (m2 < 3.3e38f) && (dl > 1.0e19f || m2 <= dl * dl * 0.9999f);

    // --- rare fallback: rings R>=2, fresh per-ring locals (disjoint) ---
    for (int R = 2; R < G && !done; ++R) {
        float f0 = 3.4e38f, f1 = 3.4e38f, f2 = 3.4e38f;
        int fi0 = 0x7fffffff, fi1 = 0x7fffffff, fi2 = 0x7fffffff;
        auto lexF = [&](float d, int ix) {
            bool lt0 = (d < f0) || (d == f0 && ix < fi0);
            bool lt1 = (d < f1) || (d == f1 && ix < fi1);
            bool lt2 = (d < f2) || (d == f2 && ix < fi2);
            f2 = lt1 ? f1 : (lt2 ? d : f2);  fi2 = lt1 ? fi1 : (lt2 ? ix : fi2);
            f1 = lt0 ? f0 : (lt1 ? d : f1);  fi1 = lt0 ? fi0 : (lt1 ? ix : fi1);
            f0 = lt0 ? d : f0;               fi0 = lt0 ? ix : fi0;
        };
        auto scanF = [&](int p0, int p1) {
            for (int p = p0; p < p1; ++p) {
                float4 s = sb[p];
                float ddx = tx - s.x, ddy = ty - s.y, ddz = tz - s.z;
                float d2 = __fadd_rn(__fadd_rn(__fmul_rn(ddx,ddx), __fmul_rn(ddy,ddy)),
                                     __fmul_rn(ddz,ddz));
                lexF(d2, __float_as_int(s.w));
            }
        };
        int p0a = 0, p1a = 0, p0b = 0, p1b = 0;
        int nm = 0, k = 0;
        int zlo = max(cz - R, 0), zhi = min(cz + R, G - 1);
        int ylo = max(cy - R, 0), yhi = min(cy + R, G - 1);
        for (int z = zlo; z <= zhi; ++z) {
            bool zedge = (z == cz - R) || (z == cz + R);
            for (int y = ylo; y <= yhi; ++y) {
                bool edge = zedge || (y == cy - R) || (y == cy + R);
                int rowb = (z*G + y)*G;
                if (edge) {
                    int x0 = max(cx - R, 0), x1 = min(cx + R, G - 1);
                    if ((k & 7) == l) {
                        int p0 = stb[rowb + x0], p1 = stb[rowb + x1 + 1];
                        if (nm == 0)      { p0a = p0; p1a = p1; }
                        else if (nm == 1) { p0b = p0; p1b = p1; }
                        else scanF(p0, p1);
                        ++nm;
                    }
                    ++k;
                } else {
                    int xm = cx - R, xp = cx + R;
                    if (xm >= 0) {
                        if ((k & 7) == l) {
                            int p0 = stb[rowb + xm], p1 = stb[rowb + xm + 1];
                            if (nm == 0)      { p0a = p0; p1a = p1; }
                            else if (nm == 1) { p0b = p0; p1b = p1; }
                            else scanF(p0, p1);
                            ++nm;
                        }
                        ++k;
                    }
                    if (xp <= G - 1) {
                        if ((k & 7) == l) {
                            int p0 = stb[rowb + xp], p1 = stb[rowb + xp + 1];
                            if (nm == 0)      { p0a = p0; p1a = p1; }
                            else if (nm == 1) { p0b = p0; p1b = p1; }
                            else scanF(p0, p1);
                            ++nm;
                        }
                        ++k;
                    }
                }
            }
        }
        if (nm > 0) scanF(p0a, p1a);
        if (nm > 1) scanF(p0b, p1b);
        // merge ring locals (disjoint across lanes), then fold into shared
        #pragma unroll
        for (int mask = 1; mask <= 4; mask <<= 1) {
            float o0 = __shfl_xor(f0, mask), o1 = __shfl_xor(f1, mask), o2 = __shfl_xor(f2, mask);
            int   q0 = __shfl_xor(fi0, mask), q1 = __shfl_xor(fi1, mask), q2 = __shfl_xor(fi2, mask);
            lexF(o0, q0); lexF(o1, q1); lexF(o2, q2);
        }
        lexM(f0, fi0); lexM(f1, fi1); lexM(f2, fi2);   // new points: distinct from shared
        float dlr = faceD(R);
        done = (m2 < 3.3e38f) && (dlr > 1.0e19f || m2 <= dlr * dlr * 0.9999f);
    }

    float d0 = sqrtf(fmaxf(m0, 0.f));
    float d1 = sqrtf(fmaxf(m1, 0.f));
    float d2s = sqrtf(fmaxf(m2, 0.f));
    float w0 = 1.f / (d0 + 1e-8f);
    float w1 = 1.f / (d1 + 1e-8f);
    float w2 = 1.f / (d2s + 1e-8f);
    float wsum = w0 + w1 + w2;
    w0 /= wsum; w1 /= wsum; w2 /= wsum;

    // fused gather: lane l covers channels [l*16, l*16+16)
    int base = b * Ns * 128;
    const float4* F0 = (const float4*)&feats[base + j0 * 128];
    const float4* F1 = (const float4*)&feats[base + j1 * 128];
    const float4* F2 = (const float4*)&feats[base + j2 * 128];
    float4* O = (float4*)&out[tg * 128];
    #pragma unroll
    for (int q = 0; q < 4; ++q) {
        int ci = l * 4 + q;
        float4 a = F0[ci], bb = F1[ci], cc = F2[ci];
        float4 o;
        o.x = w0*a.x + w1*bb.x + w2*cc.x;
        o.y = w0*a.y + w1*bb.y + w2*cc.y;
        o.z = w0*a.z + w1*bb.z + w2*cc.z;
        o.w = w0*a.w + w1*bb.w + w2*cc.w;
        O[ci] = o;
    }
}

// ---------- GEMM A (MFMA bf16, +fused BN stats): H = [L|R] @ W^T ---------- (R9-proven)
__global__ __launch_bounds__(256)
void gemm_a_kernel(const float* __restrict__ L, const float* __restrict__ R,
                   const float* __restrict__ W, float* __restrict__ H,
                   float* __restrict__ st) {
    __shared__ short Asm[4096];
    __shared__ short Bsm[2048];
    int tid = threadIdx.x;
    int lane = tid & 63, w = tid >> 6;
    int m16 = lane & 15, quad = lane >> 4;
    int rowBase = blockIdx.y * 128;
    int colBase = blockIdx.x * 64;
    f32x4 acc[2][4] = {};
    for (int k0 = 0; k0 < 256; k0 += 32) {
        #pragma unroll
        for (int i = 0; i < 2; ++i) {
            int u = tid + i * 256;
            int r = u >> 2, g = u & 3;
            const float* p = (k0 < 128) ? &L[(rowBase + r) * 128 + k0 + g * 8]
                                        : &R[(rowBase + r) * 128 + (k0 - 128) + g * 8];
            float4 x = *(const float4*)p, y = *(const float4*)(p + 4);
            uint4 pk = make_uint4(pack2(x.x, x.y), pack2(x.z, x.w),
                                  pack2(y.x, y.y), pack2(y.z, y.w));
            int blk = (r >> 4) * 64 + (r & 15) * 4 + g;
            *(uint4*)&Asm[blk * 8] = pk;
        }
        {
            int n = tid >> 2, g = tid & 3;
            const float* p = &W[(colBase + n) * 256 + k0 + g * 8];
            float4 x = *(const float4*)p, y = *(const float4*)(p + 4);
            uint4 pk = make_uint4(pack2(x.x, x.y), pack2(x.z, x.w),
                                  pack2(y.x, y.y), pack2(y.z, y.w));
            int blk = (n >> 4) * 64 + (n & 15) * 4 + g;
            *(uint4*)&Bsm[blk * 8] = pk;
        }
        __syncthreads();
        bf16x8 a0 = *(const bf16x8*)&Asm[((2 * w + 0) * 64 + m16 * 4 + quad) * 8];
        bf16x8 a1 = *(const bf16x8*)&Asm[((2 * w + 1) * 64 + m16 * 4 + quad) * 8];
        #pragma unroll
        for (int ct = 0; ct < 4; ++ct) {
            bf16x8 bf = *(const bf16x8*)&Bsm[(ct * 64 + m16 * 4 + quad) * 8];
            acc[0][ct] = __builtin_amdgcn_mfma_f32_16x16x32_bf16(a0, bf, acc[0][ct], 0, 0, 0);
            acc[1][ct] = __builtin_amdgcn_mfma_f32_16x16x32_bf16(a1, bf, acc[1][ct], 0, 0, 0);
        }
        __syncthreads();
    }
    #pragma unroll
    for (int rt = 0; rt < 2; ++rt)
        #pragma unroll
        for (int r = 0; r < 4; ++r) {
            int row = rowBase + (2 * w + rt) * 16 + quad * 4 + r;
            #pragma unroll
            for (int ct = 0; ct < 4; ++ct)
                H[row * 128 + colBase + ct * 16 + m16] = acc[rt][ct][r];
        }
    float* ssum = (float*)Asm;
    float* ssq  = (float*)Asm + 1024;
    #pragma unroll
    for (int ct = 0; ct < 4; ++ct) {
        float s = 0.f, q = 0.f;
        #pragma unroll
        for (int rt = 0; rt < 2; ++rt)
            #pragma unroll
            for (int r = 0; r < 4; ++r) {
                float v = acc[rt][ct][r];
                s += v; q += v * v;
            }
        ssum[(w * 4 + quad) * 64 + ct * 16 + m16] = s;
        ssq [(w * 4 + quad) * 64 + ct * 16 + m16] = q;
    }
    __syncthreads();
    if (tid < 64) {
        float s = 0.f, q = 0.f;
        #pragma unroll
        for (int i = 0; i < 16; ++i) { s += ssum[i * 64 + tid]; q += ssq[i * 64 + tid]; }
        atomicAdd(&st[colBase + tid], s);
        atomicAdd(&st[128 + colBase + tid], q);
    }
}

// ---------- GEMM B (MFMA bf16, finalize fused) ---------- (R12-proven)
__global__ __launch_bounds__(256)
void gemm_b_kernel(const float* __restrict__ Hin, const float* __restrict__ st,
                   const float* __restrict__ gam, const float* __restrict__ bet,
                   float invN, const float* __restrict__ W,
                   const float* __restrict__ bias, float* __restrict__ out) {
    __shared__ short Asm[4096];
    __shared__ short Bsm[2048];
    __shared__ float ssc[128], ssf[128];
    int tid = threadIdx.x;
    if (tid < 128) {
        float mu = st[tid] * invN;
        float var = st[128 + tid] * invN - mu * mu;
        float rstd = rsqrtf(fmaxf(var, 0.f) + 1e-5f);
        float sc = rstd * gam[tid];
        ssc[tid] = sc;
        ssf[tid] = bet[tid] - mu * sc;
    }
    __syncthreads();
    int lane = tid & 63, w = tid >> 6;
    int m16 = lane & 15, quad = lane >> 4;
    int rowBase = blockIdx.y * 128;
    int colBase = blockIdx.x * 64;
    f32x4 acc[2][4] = {};
    for (int k0 = 0; k0 < 128; k0 += 32) {
        #pragma unroll
        for (int i = 0; i < 2; ++i) {
            int u = tid + i * 256;
            int r = u >> 2, g = u & 3;
            int c = k0 + g * 8;
            const float* p = &Hin[(rowBase + r) * 128 + c];
            float4 x = *(const float4*)p, y = *(const float4*)(p + 4);
            float h0 = fmaxf(x.x * ssc[c+0] + ssf[c+0], 0.f);
            float h1 = fmaxf(x.y * ssc[c+1] + ssf[c+1], 0.f);
            float h2 = fmaxf(x.z * ssc[c+2] + ssf[c+2], 0.f);
            float h3 = fmaxf(x.w * ssc[c+3] + ssf[c+3], 0.f);
            float h4 = fmaxf(y.x * ssc[c+4] + ssf[c+4], 0.f);
            float h5 = fmaxf(y.y * ssc[c+5] + ssf[c+5], 0.f);
            float h6 = fmaxf(y.z * ssc[c+6] + ssf[c+6], 0.f);
            float h7 = fmaxf(y.w * ssc[c+7] + ssf[c+7], 0.f);
            uint4 pk = make_uint4(pack2(h0, h1), pack2(h2, h3),
                                  pack2(h4, h5), pack2(h6, h7));
            int blk = (r >> 4) * 64 + (r & 15) * 4 + g;
            *(uint4*)&Asm[blk * 8] = pk;
        }
        {
            int n = tid >> 2, g = tid & 3;
            const float* p = &W[(colBase + n) * 128 + k0 + g * 8];
            float4 x = *(const float4*)p, y = *(const float4*)(p + 4);
            uint4 pk = make_uint4(pack2(x.x, x.y), pack2(x.z, x.w),
                                  pack2(y.x, y.y), pack2(y.z, y.w));
            int blk = (n >> 4) * 64 + (n & 15) * 4 + g;
            *(uint4*)&Bsm[blk * 8] = pk;
        }
        __syncthreads();
        bf16x8 a0 = *(const bf16x8*)&Asm[((2 * w + 0) * 64 + m16 * 4 + quad) * 8];
        bf16x8 a1 = *(const bf16x8*)&Asm[((2 * w + 1) * 64 + m16 * 4 + quad) * 8];
        #pragma unroll
        for (int ct = 0; ct < 4; ++ct) {
            bf16x8 bf = *(const bf16x8*)&Bsm[(ct * 64 + m16 * 4 + quad) * 8];
            acc[0][ct] = __builtin_amdgcn_mfma_f32_16x16x32_bf16(a0, bf, acc[0][ct], 0, 0, 0);
            acc[1][ct] = __builtin_amdgcn_mfma_f32_16x16x32_bf16(a1, bf, acc[1][ct], 0, 0, 0);
        }
        __syncthreads();
    }
    #pragma unroll
    for (int ct = 0; ct < 4; ++ct) {
        float bv = bias[colBase + ct * 16 + m16];
        #pragma unroll
        for (int rt = 0; rt < 2; ++rt)
            #pragma unroll
            for (int r = 0; r < 4; ++r) {
                int row = rowBase + (2 * w + rt) * 16 + quad * 4 + r;
                out[row * 128 + colBase + ct * 16 + m16] = acc[rt][ct][r] + bv;
            }
    }
}

extern "C" void kernel_launch(void* const* d_in, const int* in_sizes, int n_in,
                              void* d_out, int out_size, void* d_ws, size_t ws_size,
                              hipStream_t stream) {
    const float* pts_r1 = (const float*)d_in[0];   // (2,8192,3)
    const float* pts_r2 = (const float*)d_in[1];   // (2,4096,3)
    const float* pts_r4 = (const float*)d_in[2];   // (2,2048,3)
    const float* feat0  = (const float*)d_in[3];   // (16384,128)
    const float* feat1  = (const float*)d_in[4];   // (8192,128)
    const float* feat2  = (const float*)d_in[5];   // (4096,128)
    const float* w3a = (const float*)d_in[6];      // (128,256)
    const float* g3  = (const float*)d_in[7];
    const float* b3  = (const float*)d_in[8];
    const float* w3b = (const float*)d_in[9];      // (128,128)
    const float* bb3 = (const float*)d_in[10];
    const float* w4a = (const float*)d_in[11];     // (128,256)
    const float* g4  = (const float*)d_in[12];
    const float* b4  = (const float*)d_in[13];
    const float* w4b = (const float*)d_in[14];     // (128,128)
    const float* bb4 = (const float*)d_in[15];

    float* wsf = (float*)d_ws;
    float4* sorted4 = (float4*)(wsf + 0);        // 2*2048 float4
    float4* sorted2 = (float4*)(wsf + 16384);    // 2*4096 float4
    int*   start4   = (int*)(wsf + 49152);       // 2*513 -> pad 1152
    int*   start2   = (int*)(wsf + 50304);       // 2*1001 -> pad 2048
    float* st1 = wsf + 52352;                    // 256 (sum | sumsq)
    float* st2 = wsf + 52864;                    // 256
    float* f2i = wsf + 53376;                    // 8192*128
    float* H1  = wsf + 1101952;                  // 8192*128
    float* n3  = wsf + 2150528;                  // 8192*128
    float* n3i = wsf + 53376;                    // 16384*128 (over f2i+H1, both dead)
    float* H2  = wsf + 2150528;                  // 16384*128 (over n3, dead by then)

    // 1. build both grids (+zero stats)
    build_grid_kernel<<<4, 1024, 0, stream>>>(pts_r4, pts_r2, sorted4, start4,
                                              sorted2, start2, st1, st2);
    // 2. interp #1: feat2 (pts_r4 grid, G=8) -> pts_r2 targets
    nn_query_gather_kernel<8><<<dim3(128, 2), 256, 0, stream>>>(pts_r2, 4096, sorted4,
                                                                start4, 2048, feat2, f2i);
    // 3. fnode 3
    gemm_a_kernel<<<dim3(2, 64), 256, 0, stream>>>(feat1, f2i, w3a, H1, st1);
    gemm_b_kernel<<<dim3(2, 64), 256, 0, stream>>>(H1, st1, g3, b3, 1.f / 8192.f,
                                                   w3b, bb3, n3);
    // 4. interp #2: n3 (pts_r2 grid, G=10) -> pts_r1 targets
    nn_query_gather_kernel<10><<<dim3(256, 2), 256, 0, stream>>>(pts_r1, 8192, sorted2,
                                                                 start2, 4096, n3, n3i);
    // 5. fnode 4
    gemm_a_kernel<<<dim3(2, 128), 256, 0, stream>>>(feat0, n3i, w4a, H2, st2);
    gemm_b_kernel<<<dim3(2, 128), 256, 0, stream>>>(H2, st2, g4, b4, 1.f / 16384.f,
                                                    w4b, bb4, (float*)d_out);
}

// Round 14
// 191.823 us; speedup vs baseline: 1.5513x; 1.1312x over previous
//
#include <hip/hip_runtime.h>

// All tensors FLOAT32 (proven R5). GEMMs: bf16 MFMA (err 0.031 < 0.108 thr).
// Interp: brute force (R9-proven; VALU-issue-bound at 74% busy beats the
// grid family's latency/divergence shape -- R10-R13 measured). d2 exact rn
// ((dx2+dy2)+dz2, no FMA); strict-< insertion + ascending enumeration ==
// lax.top_k stable tie-break. Value updates via min/med3 (bit-equivalent).
// Harness floor measured: ~46us ws-poison fill + restores + ~3us/launch.

typedef __attribute__((ext_vector_type(8))) short bf16x8;
typedef __attribute__((ext_vector_type(4))) float f32x4;

__device__ __forceinline__ unsigned short f2bf(float f) {
    union { float f; unsigned u; } v; v.f = f;
    return (unsigned short)((v.u + 0x7fffu + ((v.u >> 16) & 1u)) >> 16); // RNE
}
__device__ __forceinline__ unsigned pack2(float a, float b) {
    return (unsigned)f2bf(a) | ((unsigned)f2bf(b) << 16);
}

// ---------- prep: xyz -> padded float4, zero BN-stat accumulators ----------
__global__ __launch_bounds__(256)
void prep_kernel(const float* __restrict__ p1, const float* __restrict__ p2,
                 const float* __restrict__ p4,
                 float4* __restrict__ x1, float4* __restrict__ x2, float4* __restrict__ x4,
                 float* __restrict__ st1, float* __restrict__ st2) {
    int i = blockIdx.x * 256 + threadIdx.x;
    if (i < 256) { st1[i] = 0.f; st2[i] = 0.f; }
    const int P1 = 16384, P2 = 8192, P4 = 4096;
    if (i < P1) {
        x1[i] = make_float4(p1[i*3], p1[i*3+1], p1[i*3+2], 0.f);
    } else if (i < P1 + P2) {
        int j = i - P1;
        x2[j] = make_float4(p2[j*3], p2[j*3+1], p2[j*3+2], 0.f);
    } else if (i < P1 + P2 + P4) {
        int j = i - P1 - P2;
        x4[j] = make_float4(p4[j*3], p4[j*3+1], p4[j*3+2], 0.f);
    }
}

// ---------- 3-NN interpolate (R9-proven shape): 8 targets x 32 chunks ----------
template<int CHUNK>
__global__ __launch_bounds__(256)
void nn_interp_kernel(const float4* __restrict__ tgt, int Nt,
                      const float4* __restrict__ src, int Ns,
                      const float* __restrict__ feats,
                      float* __restrict__ out) {
    int tid = threadIdx.x;
    int pl = tid & 7, ch = tid >> 3;
    int b = blockIdx.y;
    int tbase = blockIdx.x * 8;
    float4 ta = tgt[b * Nt + tbase + pl];

    float a0=3.4e38f, a1=3.4e38f, a2=3.4e38f;
    int ia0=0, ia1=0, ia2=0;
    const float4* sp = src + b * Ns + ch * CHUNK;
    #pragma unroll 8
    for (int j = 0; j < CHUNK; ++j) {
        float4 s = sp[j];
        int idx = ch * CHUNK + j;
        float dx = ta.x - s.x, dy = ta.y - s.y, dz = ta.z - s.z;
        float d2 = __fadd_rn(__fadd_rn(__fmul_rn(dx,dx), __fmul_rn(dy,dy)),
                             __fmul_rn(dz,dz));
        bool c0 = d2 < a0, c1 = d2 < a1, c2 = d2 < a2;
        // values via min/med3 (bit-equivalent to select chain; finite inputs)
        float na2 = fminf(a2, fmaxf(a1, d2));
        float na1 = __builtin_amdgcn_fmed3f(a0, a1, d2);
        float na0 = fminf(a0, d2);
        ia2 = c1 ? ia1 : (c2 ? idx : ia2);
        ia1 = c0 ? ia0 : (c1 ? idx : ia1);
        ia0 = c0 ? idx : ia0;
        a0 = na0; a1 = na1; a2 = na2;
    }

    __shared__ float sd[8][32][3];
    __shared__ int   si[8][32][3];
    __shared__ float pd[8][4][3];
    __shared__ int   pi[8][4][3];
    __shared__ float sw[8][3];
    __shared__ int   sg[8][3];
    sd[pl][ch][0]=a0; sd[pl][ch][1]=a1; sd[pl][ch][2]=a2;
    si[pl][ch][0]=ia0; si[pl][ch][1]=ia1; si[pl][ch][2]=ia2;
    __syncthreads();

    // level 1: 32 threads = 8 targets x 4 mergers; each merges 8 chunks ascending
    if (tid < 32) {
        int tt = tid >> 2, m = tid & 3;
        float m0=3.4e38f, m1=3.4e38f, m2=3.4e38f;
        int j0=0, j1=0, j2=0;
        #pragma unroll
        for (int cc = m * 8; cc < m * 8 + 8; ++cc) {
            #pragma unroll
            for (int k = 0; k < 3; ++k) {
                float d = sd[tt][cc][k]; int ix = si[tt][cc][k];
                bool c0 = d < m0, c1 = d < m1, c2 = d < m2;
                m2 = c1 ? m1 : (c2 ? d : m2);  j2 = c1 ? j1 : (c2 ? ix : j2);
                m1 = c0 ? m0 : (c1 ? d : m1);  j1 = c0 ? j0 : (c1 ? ix : j1);
                m0 = c0 ? d : m0;              j0 = c0 ? ix : j0;
            }
        }
        pd[tt][m][0]=m0; pd[tt][m][1]=m1; pd[tt][m][2]=m2;
        pi[tt][m][0]=j0; pi[tt][m][1]=j1; pi[tt][m][2]=j2;
    }
    __syncthreads();

    // level 2: 8 threads merge 4 partials ascending, compute weights
    if (tid < 8) {
        float m0=3.4e38f, m1=3.4e38f, m2=3.4e38f;
        int j0=0, j1=0, j2=0;
        #pragma unroll
        for (int m = 0; m < 4; ++m) {
            #pragma unroll
            for (int k = 0; k < 3; ++k) {
                float d = pd[tid][m][k]; int ix = pi[tid][m][k];
                bool c0 = d < m0, c1 = d < m1, c2 = d < m2;
                m2 = c1 ? m1 : (c2 ? d : m2);  j2 = c1 ? j1 : (c2 ? ix : j2);
                m1 = c0 ? m0 : (c1 ? d : m1);  j1 = c0 ? j0 : (c1 ? ix : j1);
                m0 = c0 ? d : m0;              j0 = c0 ? ix : j0;
            }
        }
        float d0 = sqrtf(fmaxf(m0, 0.f));
        float d1 = sqrtf(fmaxf(m1, 0.f));
        float d2 = sqrtf(fmaxf(m2, 0.f));
        float w0 = 1.f / (d0 + 1e-8f);
        float w1 = 1.f / (d1 + 1e-8f);
        float w2 = 1.f / (d2 + 1e-8f);
        float wsum = w0 + w1 + w2;
        sw[tid][0] = w0 / wsum; sw[tid][1] = w1 / wsum; sw[tid][2] = w2 / wsum;
        sg[tid][0] = j0; sg[tid][1] = j1; sg[tid][2] = j2;
    }
    __syncthreads();

    // gather: 8 targets x 64 channel-pairs
    for (int e = tid; e < 8 * 64; e += 256) {
        int tt = e >> 6, cp = (e & 63) * 2;
        int base = b * Ns * 128;
        float2 f0  = *(const float2*)&feats[base + sg[tt][0] * 128 + cp];
        float2 f1  = *(const float2*)&feats[base + sg[tt][1] * 128 + cp];
        float2 f2v = *(const float2*)&feats[base + sg[tt][2] * 128 + cp];
        float2 o;
        o.x = sw[tt][0] * f0.x + sw[tt][1] * f1.x + sw[tt][2] * f2v.x;
        o.y = sw[tt][0] * f0.y + sw[tt][1] * f1.y + sw[tt][2] * f2v.y;
        *(float2*)&out[(b * Nt + tbase + tt) * 128 + cp] = o;
    }
}

// ---------- GEMM A (MFMA bf16, +fused BN stats): H = [L|R] @ W^T ---------- (R9-proven)
__global__ __launch_bounds__(256)
void gemm_a_kernel(const float* __restrict__ L, const float* __restrict__ R,
                   const float* __restrict__ W, float* __restrict__ H,
                   float* __restrict__ st) {
    __shared__ short Asm[4096];
    __shared__ short Bsm[2048];
    int tid = threadIdx.x;
    int lane = tid & 63, w = tid >> 6;
    int m16 = lane & 15, quad = lane >> 4;
    int rowBase = blockIdx.y * 128;
    int colBase = blockIdx.x * 64;
    f32x4 acc[2][4] = {};
    for (int k0 = 0; k0 < 256; k0 += 32) {
        #pragma unroll
        for (int i = 0; i < 2; ++i) {
            int u = tid + i * 256;
            int r = u >> 2, g = u & 3;
            const float* p = (k0 < 128) ? &L[(rowBase + r) * 128 + k0 + g * 8]
                                        : &R[(rowBase + r) * 128 + (k0 - 128) + g * 8];
            float4 x = *(const float4*)p, y = *(const float4*)(p + 4);
            uint4 pk = make_uint4(pack2(x.x, x.y), pack2(x.z, x.w),
                                  pack2(y.x, y.y), pack2(y.z, y.w));
            int blk = (r >> 4) * 64 + (r & 15) * 4 + g;
            *(uint4*)&Asm[blk * 8] = pk;
        }
        {
            int n = tid >> 2, g = tid & 3;
            const float* p = &W[(colBase + n) * 256 + k0 + g * 8];
            float4 x = *(const float4*)p, y = *(const float4*)(p + 4);
            uint4 pk = make_uint4(pack2(x.x, x.y), pack2(x.z, x.w),
                                  pack2(y.x, y.y), pack2(y.z, y.w));
            int blk = (n >> 4) * 64 + (n & 15) * 4 + g;
            *(uint4*)&Bsm[blk * 8] = pk;
        }
        __syncthreads();
        bf16x8 a0 = *(const bf16x8*)&Asm[((2 * w + 0) * 64 + m16 * 4 + quad) * 8];
        bf16x8 a1 = *(const bf16x8*)&Asm[((2 * w + 1) * 64 + m16 * 4 + quad) * 8];
        #pragma unroll
        for (int ct = 0; ct < 4; ++ct) {
            bf16x8 bf = *(const bf16x8*)&Bsm[(ct * 64 + m16 * 4 + quad) * 8];
            acc[0][ct] = __builtin_amdgcn_mfma_f32_16x16x32_bf16(a0, bf, acc[0][ct], 0, 0, 0);
            acc[1][ct] = __builtin_amdgcn_mfma_f32_16x16x32_bf16(a1, bf, acc[1][ct], 0, 0, 0);
        }
        __syncthreads();
    }
    #pragma unroll
    for (int rt = 0; rt < 2; ++rt)
        #pragma unroll
        for (int r = 0; r < 4; ++r) {
            int row = rowBase + (2 * w + rt) * 16 + quad * 4 + r;
            #pragma unroll
            for (int ct = 0; ct < 4; ++ct)
                H[row * 128 + colBase + ct * 16 + m16] = acc[rt][ct][r];
        }
    float* ssum = (float*)Asm;
    float* ssq  = (float*)Asm + 1024;
    #pragma unroll
    for (int ct = 0; ct < 4; ++ct) {
        float s = 0.f, q = 0.f;
        #pragma unroll
        for (int rt = 0; rt < 2; ++rt)
            #pragma unroll
            for (int r = 0; r < 4; ++r) {
                float v = acc[rt][ct][r];
                s += v; q += v * v;
            }
        ssum[(w * 4 + quad) * 64 + ct * 16 + m16] = s;
        ssq [(w * 4 + quad) * 64 + ct * 16 + m16] = q;
    }
    __syncthreads();
    if (tid < 64) {
        float s = 0.f, q = 0.f;
        #pragma unroll
        for (int i = 0; i < 16; ++i) { s += ssum[i * 64 + tid]; q += ssq[i * 64 + tid]; }
        atomicAdd(&st[colBase + tid], s);
        atomicAdd(&st[128 + colBase + tid], q);
    }
}

// ---------- GEMM B (MFMA bf16, finalize fused) ---------- (R12/R13-proven)
__global__ __launch_bounds__(256)
void gemm_b_kernel(const float* __restrict__ Hin, const float* __restrict__ st,
                   const float* __restrict__ gam, const float* __restrict__ bet,
                   float invN, const float* __restrict__ W,
                   const float* __restrict__ bias, float* __restrict__ out) {
    __shared__ short Asm[4096];
    __shared__ short Bsm[2048];
    __shared__ float ssc[128], ssf[128];
    int tid = threadIdx.x;
    if (tid < 128) {
        float mu = st[tid] * invN;
        float var = st[128 + tid] * invN - mu * mu;
        float rstd = rsqrtf(fmaxf(var, 0.f) + 1e-5f);
        float sc = rstd * gam[tid];
        ssc[tid] = sc;
        ssf[tid] = bet[tid] - mu * sc;
    }
    __syncthreads();
    int lane = tid & 63, w = tid >> 6;
    int m16 = lane & 15, quad = lane >> 4;
    int rowBase = blockIdx.y * 128;
    int colBase = blockIdx.x * 64;
    f32x4 acc[2][4] = {};
    for (int k0 = 0; k0 < 128; k0 += 32) {
        #pragma unroll
        for (int i = 0; i < 2; ++i) {
            int u = tid + i * 256;
            int r = u >> 2, g = u & 3;
            int c = k0 + g * 8;
            const float* p = &Hin[(rowBase + r) * 128 + c];
            float4 x = *(const float4*)p, y = *(const float4*)(p + 4);
            float h0 = fmaxf(x.x * ssc[c+0] + ssf[c+0], 0.f);
            float h1 = fmaxf(x.y * ssc[c+1] + ssf[c+1], 0.f);
            float h2 = fmaxf(x.z * ssc[c+2] + ssf[c+2], 0.f);
            float h3 = fmaxf(x.w * ssc[c+3] + ssf[c+3], 0.f);
            float h4 = fmaxf(y.x * ssc[c+4] + ssf[c+4], 0.f);
            float h5 = fmaxf(y.y * ssc[c+5] + ssf[c+5], 0.f);
            float h6 = fmaxf(y.z * ssc[c+6] + ssf[c+6], 0.f);
            float h7 = fmaxf(y.w * ssc[c+7] + ssf[c+7], 0.f);
            uint4 pk = make_uint4(pack2(h0, h1), pack2(h2, h3),
                                  pack2(h4, h5), pack2(h6, h7));
            int blk = (r >> 4) * 64 + (r & 15) * 4 + g;
            *(uint4*)&Asm[blk * 8] = pk;
        }
        {
            int n = tid >> 2, g = tid & 3;
            const float* p = &W[(colBase + n) * 128 + k0 + g * 8];
            float4 x = *(const float4*)p, y = *(const float4*)(p + 4);
            uint4 pk = make_uint4(pack2(x.x, x.y), pack2(x.z, x.w),
                                  pack2(y.x, y.y), pack2(y.z, y.w));
            int blk = (n >> 4) * 64 + (n & 15) * 4 + g;
            *(uint4*)&Bsm[blk * 8] = pk;
        }
        __syncthreads();
        bf16x8 a0 = *(const bf16x8*)&Asm[((2 * w + 0) * 64 + m16 * 4 + quad) * 8];
        bf16x8 a1 = *(const bf16x8*)&Asm[((2 * w + 1) * 64 + m16 * 4 + quad) * 8];
        #pragma unroll
        for (int ct = 0; ct < 4; ++ct) {
            bf16x8 bf = *(const bf16x8*)&Bsm[(ct * 64 + m16 * 4 + quad) * 8];
            acc[0][ct] = __builtin_amdgcn_mfma_f32_16x16x32_bf16(a0, bf, acc[0][ct], 0, 0, 0);
            acc[1][ct] = __builtin_amdgcn_mfma_f32_16x16x32_bf16(a1, bf, acc[1][ct], 0, 0, 0);
        }
        __syncthreads();
    }
    #pragma unroll
    for (int ct = 0; ct < 4; ++ct) {
        float bv = bias[colBase + ct * 16 + m16];
        #pragma unroll
        for (int rt = 0; rt < 2; ++rt)
            #pragma unroll
            for (int r = 0; r < 4; ++r) {
                int row = rowBase + (2 * w + rt) * 16 + quad * 4 + r;
                out[row * 128 + colBase + ct * 16 + m16] = acc[rt][ct][r] + bv;
            }
    }
}

extern "C" void kernel_launch(void* const* d_in, const int* in_sizes, int n_in,
                              void* d_out, int out_size, void* d_ws, size_t ws_size,
                              hipStream_t stream) {
    const float* pts_r1 = (const float*)d_in[0];   // (2,8192,3)
    const float* pts_r2 = (const float*)d_in[1];   // (2,4096,3)
    const float* pts_r4 = (const float*)d_in[2];   // (2,2048,3)
    const float* feat0  = (const float*)d_in[3];   // (16384,128)
    const float* feat1  = (const float*)d_in[4];   // (8192,128)
    const float* feat2  = (const float*)d_in[5];   // (4096,128)
    const float* w3a = (const float*)d_in[6];      // (128,256)
    const float* g3  = (const float*)d_in[7];
    const float* b3  = (const float*)d_in[8];
    const float* w3b = (const float*)d_in[9];      // (128,128)
    const float* bb3 = (const float*)d_in[10];
    const float* w4a = (const float*)d_in[11];     // (128,256)
    const float* g4  = (const float*)d_in[12];
    const float* b4  = (const float*)d_in[13];
    const float* w4b = (const float*)d_in[14];     // (128,128)
    const float* bb4 = (const float*)d_in[15];

    float* wsf = (float*)d_ws;
    float4* xyz1 = (float4*)(wsf + 0);        // 16384 pts
    float4* xyz2 = (float4*)(wsf + 65536);    // 8192 pts
    float4* xyz4 = (float4*)(wsf + 98304);    // 4096 pts
    float* f2i = wsf + 114688;                // 8192*128
    float* H1  = wsf + 1163264;               // 8192*128
    float* n3  = wsf + 2211840;               // 8192*128
    float* n3i = wsf + 114688;                // 16384*128 (over f2i+H1, both dead)
    float* H2  = wsf + 3260416;               // 16384*128
    float* st1 = wsf + 5357568;               // 256 (sum | sumsq)
    float* st2 = wsf + 5358080;               // 256

    // 1. prep: pad xyz, zero stat accumulators
    prep_kernel<<<112, 256, 0, stream>>>(pts_r1, pts_r2, pts_r4, xyz1, xyz2, xyz4, st1, st2);
    // 2. interp #1: feat2 (pts_r4) -> pts_r2 targets, CHUNK=64
    nn_interp_kernel<64><<<dim3(512, 2), 256, 0, stream>>>(xyz2, 4096, xyz4, 2048,
                                                           feat2, f2i);
    // 3. fnode 3
    gemm_a_kernel<<<dim3(2, 64), 256, 0, stream>>>(feat1, f2i, w3a, H1, st1);
    gemm_b_kernel<<<dim3(2, 64), 256, 0, stream>>>(H1, st1, g3, b3, 1.f / 8192.f,
                                                   w3b, bb3, n3);
    // 4. interp #2: n3 (pts_r2) -> pts_r1 targets, CHUNK=128
    nn_interp_kernel<128><<<dim3(1024, 2), 256, 0, stream>>>(xyz1, 8192, xyz2, 4096,
                                                             n3, n3i);
    // 5. fnode 4
    gemm_a_kernel<<<dim3(2, 128), 256, 0, stream>>>(feat0, n3i, w4a, H2, st2);
    gemm_b_kernel<<<dim3(2, 128), 256, 0, stream>>>(H2, st2, g4, b4, 1.f / 16384.f,
                                                    w4b, bb4, (float*)d_out);
}